// Round 8
// baseline (2260.967 us; speedup 1.0000x reference)
//
#include <hip/hip_runtime.h>
#include <stdint.h>

#define TT     150
#define INSZ   120
#define HID    1024
#define OUTN   35
#define NBR    8
#define TP     152     // padded time steps (19*8); mask row = 1216 B (64-aligned)
#define CH     8
#define NCHUNK 19

// ---------------- ws map (bytes) — aliased, peak 8.78 MB (verified r6/r7) --
#define SA_OFF   0
#define SB_OFF   1245184
#define PK_OFF   2490368
#define XT_OFF   3538944
#define Y_OFF    2490368
#define ACC_OFF  3866624

// ---- pack masked rows into {idx u16[NNZ_OUT], w f32[NNZ_OUT]} streams ----
template <int DIN, int NNZ_EXPECT, int NNZ_OUT, int RSTRIDE, int WOFF>
__global__ __launch_bounds__(512) void k_pack(
    const float* __restrict__ w, const void* __restrict__ maskp,
    uint8_t* __restrict__ dst) {
    const int lane = threadIdx.x & 63;
    const int wid  = __builtin_amdgcn_readfirstlane(threadIdx.x >> 6);
    const int r    = blockIdx.x * 8 + wid;
    uint16_t* di = (uint16_t*)(dst + (size_t)r * RSTRIDE);
    float*    dw = (float*)(dst + (size_t)r * RSTRIDE + WOFF);
    const unsigned char* m8  = (const unsigned char*)maskp;
    const int*           m32 = (const int*)maskp;

    int cnt = 0;
    for (int c = 0; c * 64 < DIN; ++c) {
        const int i = c * 64 + lane;
        int   mv = 0; float wv = 0.f;
        if (i < DIN) { mv = m8[(size_t)r * DIN + i]; wv = w[(size_t)r * DIN + i]; }
        const unsigned long long bal = __ballot(mv != 0);
        const int pos = __popcll(bal & ((1ull << lane) - 1ull));
        if (mv && cnt + pos < NNZ_OUT) { di[cnt + pos] = (uint16_t)i; dw[cnt + pos] = wv; }
        cnt += __popcll(bal);
    }
    if (cnt != NNZ_EXPECT) {          // masks are int32 after all
        cnt = 0;
        for (int c = 0; c * 64 < DIN; ++c) {
            const int i = c * 64 + lane;
            int   mv = 0; float wv = 0.f;
            if (i < DIN) { mv = m32[(size_t)r * DIN + i]; wv = w[(size_t)r * DIN + i]; }
            const unsigned long long bal = __ballot(mv != 0);
            const int pos = __popcll(bal & ((1ull << lane) - 1ull));
            if (mv && cnt + pos < NNZ_OUT) { di[cnt + pos] = (uint16_t)i; dw[cnt + pos] = wv; }
            cnt += __popcll(bal);
        }
    }
    for (int f = cnt + lane; f < NNZ_OUT; f += 64) { di[f] = 0; dw[f] = 0.f; }
}

// transpose x[b][0][t][i] -> xT[t][i][b], LDS-tiled (both sides coalesced)
__global__ __launch_bounds__(256) void k_tx(const float* __restrict__ x,
                                            float* __restrict__ xT) {
    const int t = blockIdx.x;
    __shared__ float tile[INSZ * 65];
    for (int e = threadIdx.x; e < INSZ * 64; e += 256) {
        const int b = e / INSZ, i = e - b * INSZ;
        tile[i * 65 + b] = x[((size_t)b * TT + t) * INSZ + i];
    }
    __syncthreads();
    for (int e = threadIdx.x; e < INSZ * 64; e += 256) {
        const int i = e >> 6, b = e & 63;
        xT[((size_t)t * INSZ + i) * 64 + b] = tile[i * 65 + b];
    }
}

// Layer 1 (dense input). All 16 (idx,w) hoisted to SGPRs for the whole
// kernel; k-outer/j-inner so the block's waves sweep the same 30 KB x_t
// window per k (L1-resident). fmac takes the weight straight from SGPR.
__global__ __launch_bounds__(512, 8) void k_l1(
    const uint8_t* __restrict__ pk,
    const float* __restrict__ bias,
    const float* __restrict__ tau_m,
    const float* __restrict__ tau_n,
    const float* __restrict__ xin,          // [T][INSZ][64]
    uint64_t* __restrict__ outm)            // [HID][TP]
{
    const int lane = threadIdx.x & 63;
    const int wid  = __builtin_amdgcn_readfirstlane(threadIdx.x >> 6); // 0..7
    const int h    = blockIdx.x;
    const int r    = h * NBR + wid;

    __shared__ float red[2][NBR * CH * 64];

    const uint16_t* pidx = (const uint16_t*)(pk + (size_t)r * 128);
    const float*    pw   = (const float*)(pk + (size_t)r * 128 + 32);
    const float* rp[16];
    float wv[16];
#pragma unroll
    for (int j = 0; j < 16; ++j) {
        const int ix = __builtin_amdgcn_readfirstlane((int)pidx[j]);
        rp[j] = xin + ix * 64;              // scalar row base
        wv[j] = pw[j];                      // scalar weight
    }

    const float be = 1.f / (1.f + expf(-tau_n[r]));
    const float om = 1.f - be;
    const float bb = bias[r];
    const float al  = 1.f / (1.f + expf(-tau_m[h]));
    const float oma = 1.f - al;

    float d = 0.f, mem = 0.f, spkprev = 0.f;

    for (int tc = 0; tc < NCHUNK; ++tc) {
        const int t0  = tc * CH;
        const int buf = tc & 1;
        float a[CH];
#pragma unroll
        for (int k = 0; k < CH; ++k) a[k] = 0.f;

#pragma unroll
        for (int k = 0; k < CH; ++k) {
            const int tofs = (t0 + k) * (INSZ * 64) + lane;
#pragma unroll
            for (int j = 0; j < 16; ++j)
                a[k] += wv[j] * rp[j][tofs];
        }

#pragma unroll
        for (int k = 0; k < CH; ++k) {
            d = be * d + om * (a[k] + bb);
            red[buf][(wid * CH + k) * 64 + lane] = d;
        }
        __syncthreads();

        if (wid == 0) {
#pragma unroll
            for (int k = 0; k < CH; ++k) {
                const float r0 = red[buf][(0 * CH + k) * 64 + lane];
                const float r1 = red[buf][(1 * CH + k) * 64 + lane];
                const float r2 = red[buf][(2 * CH + k) * 64 + lane];
                const float r3 = red[buf][(3 * CH + k) * 64 + lane];
                const float r4 = red[buf][(4 * CH + k) * 64 + lane];
                const float r5 = red[buf][(5 * CH + k) * 64 + lane];
                const float r6 = red[buf][(6 * CH + k) * 64 + lane];
                const float r7 = red[buf][(7 * CH + k) * 64 + lane];
                const float p01 = r0 + r1, p23 = r2 + r3;
                const float p45 = r4 + r5, p67 = r6 + r7;
                const float l = ((p01 + p23) + p45) + p67;
                if (t0 + k < TT) {
                    mem = al * mem + oma * l - spkprev;   // VTH = 1.0
                    spkprev = (mem > 1.0f) ? 1.f : 0.f;
                    const unsigned long long bal = __ballot(mem > 1.0f);
                    if (lane == 0) outm[(size_t)h * TP + (t0 + k)] = bal;
                }
            }
        }
    }
}

// Spike-input layer (layers 2/3) — r7-proven structure.
template <int DIN, int NNZ, int RSTRIDE, int WOFF>
__global__ __launch_bounds__(512, 8) void k_layer(
    const uint8_t* __restrict__ pk,
    const float* __restrict__ bias,
    const float* __restrict__ tau_m,
    const float* __restrict__ tau_n,
    const uint64_t* __restrict__ inm,       // [DIN][TP]
    uint64_t* __restrict__ outm)            // [HID][TP]
{
    const int lane = threadIdx.x & 63;
    const int wid  = __builtin_amdgcn_readfirstlane(threadIdx.x >> 6); // 0..7
    const int h    = blockIdx.x;
    const int r    = h * NBR + wid;

    __shared__ uint2 ent[NBR * NNZ];
    __shared__ float red[2][NBR * CH * 64];

    inm = (const uint64_t*)__builtin_assume_aligned(inm, 64);

    {
        const uint16_t* pidx = (const uint16_t*)(pk + (size_t)r * RSTRIDE);
        const float*    pw   = (const float*)(pk + (size_t)r * RSTRIDE + WOFF);
        for (int s = lane; s < NNZ; s += 64)
            ent[wid * NNZ + s] = make_uint2(__float_as_uint(pw[s]),
                                            (unsigned)pidx[s]);
    }
    __syncthreads();

    const float be = 1.f / (1.f + expf(-tau_n[r]));
    const float om = 1.f - be;
    const float bb = bias[r];
    const float al  = 1.f / (1.f + expf(-tau_m[h]));
    const float oma = 1.f - al;

    float d = 0.f, mem = 0.f, spkprev = 0.f;
    const int base = wid * NNZ;

    for (int tc = 0; tc < NCHUNK; ++tc) {
        const int t0  = tc * CH;
        const int buf = tc & 1;
        float a[CH];
#pragma unroll
        for (int k = 0; k < CH; ++k) a[k] = 0.f;

#pragma unroll 4
        for (int j = 0; j < NNZ; ++j) {
            const uint2 e  = ent[base + j];
            const int   ix = __builtin_amdgcn_readfirstlane((int)e.y);
            const float wv = __uint_as_float(e.x);
            const ulonglong4* p =
                (const ulonglong4*)(inm + (size_t)ix * TP + t0);
            const ulonglong4 ma = p[0], mb = p[1];
            const uint64_t m[CH] = {ma.x, ma.y, ma.z, ma.w,
                                    mb.x, mb.y, mb.z, mb.w};
#pragma unroll
            for (int k = 0; k < CH; ++k) {
                float s;
                asm("v_cndmask_b32 %0, 0, %1, %2"
                    : "=v"(s) : "v"(wv), "s"(m[k]));
                a[k] += s;
            }
        }

#pragma unroll
        for (int k = 0; k < CH; ++k) {
            d = be * d + om * (a[k] + bb);
            red[buf][(wid * CH + k) * 64 + lane] = d;
        }
        __syncthreads();

        if (wid == 0) {
#pragma unroll
            for (int k = 0; k < CH; ++k) {
                const float r0 = red[buf][(0 * CH + k) * 64 + lane];
                const float r1 = red[buf][(1 * CH + k) * 64 + lane];
                const float r2 = red[buf][(2 * CH + k) * 64 + lane];
                const float r3 = red[buf][(3 * CH + k) * 64 + lane];
                const float r4 = red[buf][(4 * CH + k) * 64 + lane];
                const float r5 = red[buf][(5 * CH + k) * 64 + lane];
                const float r6 = red[buf][(6 * CH + k) * 64 + lane];
                const float r7 = red[buf][(7 * CH + k) * 64 + lane];
                const float p01 = r0 + r1, p23 = r2 + r3;
                const float p45 = r4 + r5, p67 = r6 + r7;
                const float l = ((p01 + p23) + p45) + p67;
                if (t0 + k < TT) {
                    mem = al * mem + oma * l - spkprev;   // VTH = 1.0
                    spkprev = (mem > 1.0f) ? 1.f : 0.f;
                    const unsigned long long bal = __ballot(mem > 1.0f);
                    if (lane == 0) outm[(size_t)h * TP + (t0 + k)] = bal;
                }
            }
        }
    }
}

// Y[t][o][b] = wr[o] . s3(t,:,b)
__global__ __launch_bounds__(256) void k_ry(const float* __restrict__ wr,
                                            const uint64_t* __restrict__ s3m,
                                            float* __restrict__ Y) {
    const int lane  = threadIdx.x & 63;
    const int wid   = __builtin_amdgcn_readfirstlane(threadIdx.x >> 6); // 0..3
    const int o  = blockIdx.x / NCHUNK;
    const int t0 = (blockIdx.x % NCHUNK) * CH;
    s3m = (const uint64_t*)__builtin_assume_aligned(s3m, 64);
    const float* wrow = wr + (size_t)o * HID;
    __shared__ float red[4 * CH * 64];
    float acc[CH];
#pragma unroll
    for (int k = 0; k < CH; ++k) acc[k] = 0.f;
#pragma unroll 4
    for (int ii = 0; ii < HID / 4; ++ii) {
        const int i = wid * (HID / 4) + ii;
        const float wv = wrow[i];
        const ulonglong4* p = (const ulonglong4*)(s3m + (size_t)i * TP + t0);
        const ulonglong4 ma = p[0], mb = p[1];
        const uint64_t m[CH] = {ma.x, ma.y, ma.z, ma.w, mb.x, mb.y, mb.z, mb.w};
#pragma unroll
        for (int k = 0; k < CH; ++k) {
            float s;
            asm("v_cndmask_b32 %0, 0, %1, %2" : "=v"(s) : "v"(wv), "s"(m[k]));
            acc[k] += s;
        }
    }
#pragma unroll
    for (int k = 0; k < CH; ++k)
        red[(wid * CH + k) * 64 + lane] = acc[k];
    __syncthreads();
    if (wid == 0) {
#pragma unroll
        for (int k = 0; k < CH; ++k) {
            if (t0 + k >= TT) break;
            const float v = ((red[(0 * CH + k) * 64 + lane]
                            + red[(1 * CH + k) * 64 + lane])
                            + red[(2 * CH + k) * 64 + lane])
                            + red[(3 * CH + k) * 64 + lane];
            Y[((size_t)(t0 + k) * OUTN + o) * 64 + lane] = v;
        }
    }
}

// acc[o][b] = sum_t (Y + br[o]) * (1 - ar^(150-t))
__global__ void k_racc(const float* __restrict__ Y,
                       const float* __restrict__ br,
                       const float* __restrict__ tau_mr,
                       float* __restrict__ ACC) {
    const int o = blockIdx.x, lane = threadIdx.x;
    const float ar  = 1.f / (1.f + expf(-tau_mr[o]));
    const float bro = br[o];
    float acc = 0.f, q = ar;
    for (int t = TT - 1; t >= 0; --t) {
        const float y = Y[((size_t)t * OUTN + o) * 64 + lane] + bro;
        acc += y * (1.f - q);
        q *= ar;
    }
    ACC[o * 64 + lane] = acc;
}

__global__ void k_smax(const float* __restrict__ ACC, float* __restrict__ out) {
    const int b = threadIdx.x;   // 64 threads
    float v[OUTN];
    float mx = -3.4e38f;
    for (int o = 0; o < OUTN; ++o) {
        v[o] = ACC[o * 64 + b] / (float)TT;
        mx = fmaxf(mx, v[o]);
    }
    float sum = 0.f;
    for (int o = 0; o < OUTN; ++o) sum += expf(v[o] - mx);
    const float lse = mx + logf(sum);
    for (int o = 0; o < OUTN; ++o) out[b * OUTN + o] = v[o] - lse;
}

extern "C" void kernel_launch(void* const* d_in, const int* in_sizes, int n_in,
                              void* d_out, int out_size, void* d_ws,
                              size_t ws_size, hipStream_t stream) {
    (void)in_sizes; (void)n_in; (void)out_size; (void)ws_size;
    const float* x   = (const float*)d_in[0];
    const float* w1  = (const float*)d_in[1];
    const float* b1  = (const float*)d_in[2];
    const float* tm1 = (const float*)d_in[3];
    const float* tn1 = (const float*)d_in[4];
    const float* w2  = (const float*)d_in[5];
    const float* b2  = (const float*)d_in[6];
    const float* tm2 = (const float*)d_in[7];
    const float* tn2 = (const float*)d_in[8];
    const float* w3  = (const float*)d_in[9];
    const float* b3  = (const float*)d_in[10];
    const float* tm3 = (const float*)d_in[11];
    const float* tn3 = (const float*)d_in[12];
    const float* wr  = (const float*)d_in[13];
    const float* br  = (const float*)d_in[14];
    const float* tmr = (const float*)d_in[15];
    const void*  m1  = d_in[16];
    const void*  m2  = d_in[17];
    const void*  m3  = d_in[18];
    float* out = (float*)d_out;

    char* ws = (char*)d_ws;
    uint64_t* sA  = (uint64_t*)(ws + SA_OFF);   // s1m, later s3m
    uint64_t* sB  = (uint64_t*)(ws + SB_OFF);   // s2m
    uint8_t*  PK  = (uint8_t*)(ws + PK_OFF);    // PK1 / PK2 / PK3
    float*    xT  = (float*)(ws + XT_OFF);
    float*    Y   = (float*)(ws + Y_OFF);
    float*    ACC = (float*)(ws + ACC_OFF);

    // layer 1 (dense input)
    k_pack<INSZ, 15, 16, 128, 32><<<HID, 512, 0, stream>>>(w1, m1, PK);
    k_tx<<<TT, 256, 0, stream>>>(x, xT);
    k_l1<<<HID, 512, 0, stream>>>(PK, b1, tm1, tn1, xT, sA);
    // layer 2 (PK slot reused; xT/PK1 dead)
    k_pack<HID, 128, 128, 768, 256><<<HID, 512, 0, stream>>>(w2, m2, PK);
    k_layer<HID, 128, 768, 256><<<HID, 512, 0, stream>>>(
        PK, b2, tm2, tn2, sA, sB);
    // layer 3 (PK reused again; s3m over dead s1m)
    k_pack<HID, 128, 128, 768, 256><<<HID, 512, 0, stream>>>(w3, m3, PK);
    k_layer<HID, 128, 768, 256><<<HID, 512, 0, stream>>>(
        PK, b3, tm3, tn3, sB, sA);
    // readout (Y over dead PK)
    k_ry<<<OUTN * NCHUNK, 256, 0, stream>>>(wr, sA, Y);
    k_racc<<<OUTN, 64, 0, stream>>>(Y, br, tmr, ACC);
    k_smax<<<1, 64, 0, stream>>>(ACC, out);
}

// Round 9
// 1724.703 us; speedup vs baseline: 1.3109x; 1.3109x over previous
//
#include <hip/hip_runtime.h>
#include <stdint.h>

#define TT     150
#define INSZ   120
#define HID    1024
#define OUTN   35
#define NBR    8
#define TP     160     // padded time steps (10*16); mask row = 1280 B
#define CH     8       // l1 / ry chunk
#define CH2    16      // big-layer pair-chunk
#define NCHUNK 19      // l1 (8-step) chunks
#define NPASS  10      // big-layer 16-step passes

// ------------- ws map (bytes) — aliased, peak 8.91 MB -------------
// SA: s1m then s3m  [1024][160] u64 = 1,310,720
// SB: s2m                            1,310,720
// PK @2,621,440: PK1 (1,048,576) then PK2/PK3 (6,291,456, reused)
// XT @3,670,016 (right after PK1): [150][120][64] f32 = 4,608,000 (dead pre-PK2)
// Y  @2,621,440 over dead PK after layer3; ACC after Y.
#define SA_OFF   0
#define SB_OFF   1310720
#define PK_OFF   2621440
#define XT_OFF   3670016
#define Y_OFF    2621440
#define ACC_OFF  3965440

// ---- pack masked rows into {idx u16[NNZ_OUT], w f32[NNZ_OUT]} streams ----
template <int DIN, int NNZ_EXPECT, int NNZ_OUT, int RSTRIDE, int WOFF>
__global__ __launch_bounds__(512) void k_pack(
    const float* __restrict__ w, const void* __restrict__ maskp,
    uint8_t* __restrict__ dst) {
    const int lane = threadIdx.x & 63;
    const int wid  = __builtin_amdgcn_readfirstlane(threadIdx.x >> 6);
    const int r    = blockIdx.x * 8 + wid;
    uint16_t* di = (uint16_t*)(dst + (size_t)r * RSTRIDE);
    float*    dw = (float*)(dst + (size_t)r * RSTRIDE + WOFF);
    const unsigned char* m8  = (const unsigned char*)maskp;
    const int*           m32 = (const int*)maskp;

    int cnt = 0;
    for (int c = 0; c * 64 < DIN; ++c) {
        const int i = c * 64 + lane;
        int   mv = 0; float wv = 0.f;
        if (i < DIN) { mv = m8[(size_t)r * DIN + i]; wv = w[(size_t)r * DIN + i]; }
        const unsigned long long bal = __ballot(mv != 0);
        const int pos = __popcll(bal & ((1ull << lane) - 1ull));
        if (mv && cnt + pos < NNZ_OUT) { di[cnt + pos] = (uint16_t)i; dw[cnt + pos] = wv; }
        cnt += __popcll(bal);
    }
    if (cnt != NNZ_EXPECT) {          // masks are int32 after all
        cnt = 0;
        for (int c = 0; c * 64 < DIN; ++c) {
            const int i = c * 64 + lane;
            int   mv = 0; float wv = 0.f;
            if (i < DIN) { mv = m32[(size_t)r * DIN + i]; wv = w[(size_t)r * DIN + i]; }
            const unsigned long long bal = __ballot(mv != 0);
            const int pos = __popcll(bal & ((1ull << lane) - 1ull));
            if (mv && cnt + pos < NNZ_OUT) { di[cnt + pos] = (uint16_t)i; dw[cnt + pos] = wv; }
            cnt += __popcll(bal);
        }
    }
    for (int f = cnt + lane; f < NNZ_OUT; f += 64) { di[f] = 0; dw[f] = 0.f; }
}

// transpose x[b][0][t][i] -> xT[t][i][b], LDS-tiled
__global__ __launch_bounds__(256) void k_tx(const float* __restrict__ x,
                                            float* __restrict__ xT) {
    const int t = blockIdx.x;
    __shared__ float tile[INSZ * 65];
    for (int e = threadIdx.x; e < INSZ * 64; e += 256) {
        const int b = e / INSZ, i = e - b * INSZ;
        tile[i * 65 + b] = x[((size_t)b * TT + t) * INSZ + i];
    }
    __syncthreads();
    for (int e = threadIdx.x; e < INSZ * 64; e += 256) {
        const int i = e >> 6, b = e & 63;
        xT[((size_t)t * INSZ + i) * 64 + b] = tile[i * 65 + b];
    }
}

// Layer 1 (dense input). 16 (row-base, weight) hoisted to scalars for the
// whole kernel. k-loop is unroll(1) with the d-recursion folded in, so at
// most 16 load results are live -> cannot spill (r8 lesson).
__global__ __launch_bounds__(512, 8) void k_l1(
    const uint8_t* __restrict__ pk,
    const float* __restrict__ bias,
    const float* __restrict__ tau_m,
    const float* __restrict__ tau_n,
    const float* __restrict__ xin,          // [T][INSZ][64]
    uint64_t* __restrict__ outm)            // [HID][TP]
{
    const int lane = threadIdx.x & 63;
    const int wid  = __builtin_amdgcn_readfirstlane(threadIdx.x >> 6); // 0..7
    const int h    = blockIdx.x;
    const int r    = h * NBR + wid;

    __shared__ float red[2][NBR * CH * 64];

    const uint16_t* pidx = (const uint16_t*)(pk + (size_t)r * 128);
    const float*    pw   = (const float*)(pk + (size_t)r * 128 + 32);
    const float* rp[16];
    float wv[16];
#pragma unroll
    for (int j = 0; j < 16; ++j) {
        const int ix = __builtin_amdgcn_readfirstlane((int)pidx[j]);
        rp[j] = xin + ix * 64;
        wv[j] = __uint_as_float(
            __builtin_amdgcn_readfirstlane((int)__float_as_uint(pw[j])));
    }

    const float be = 1.f / (1.f + expf(-tau_n[r]));
    const float om = 1.f - be;
    const float bb = bias[r];
    const float al  = 1.f / (1.f + expf(-tau_m[h]));
    const float oma = 1.f - al;

    float d = 0.f, mem = 0.f, spkprev = 0.f;

    for (int tc = 0; tc < NCHUNK; ++tc) {
        const int t0  = tc * CH;
        const int buf = tc & 1;

#pragma unroll 1
        for (int k = 0; k < CH; ++k) {
            const int tofs = (t0 + k) * (INSZ * 64) + lane;
            float s = 0.f;
#pragma unroll
            for (int j = 0; j < 16; ++j)
                s += wv[j] * rp[j][tofs];      // same order as reference sum
            d = be * d + om * (s + bb);
            red[buf][(wid * CH + k) * 64 + lane] = d;
        }
        __syncthreads();

        if (wid == 0) {
#pragma unroll
            for (int k = 0; k < CH; ++k) {
                const float r0 = red[buf][(0 * CH + k) * 64 + lane];
                const float r1 = red[buf][(1 * CH + k) * 64 + lane];
                const float r2 = red[buf][(2 * CH + k) * 64 + lane];
                const float r3 = red[buf][(3 * CH + k) * 64 + lane];
                const float r4 = red[buf][(4 * CH + k) * 64 + lane];
                const float r5 = red[buf][(5 * CH + k) * 64 + lane];
                const float r6 = red[buf][(6 * CH + k) * 64 + lane];
                const float r7 = red[buf][(7 * CH + k) * 64 + lane];
                const float p01 = r0 + r1, p23 = r2 + r3;
                const float p45 = r4 + r5, p67 = r6 + r7;
                const float l = ((p01 + p23) + p45) + p67;
                if (t0 + k < TT) {
                    mem = al * mem + oma * l - spkprev;   // VTH = 1.0
                    spkprev = (mem > 1.0f) ? 1.f : 0.f;
                    const unsigned long long bal = __ballot(mem > 1.0f);
                    if (lane == 0) outm[(size_t)h * TP + (t0 + k)] = bal;
                }
            }
        }
    }
}

// Spike-input layer (layers 2/3). Pair-chunk: 16 timesteps per j-sweep
// (outm has no intra-layer consumer, so red's two buffers hold the two
// 8-step halves of one pass). Passes 19 -> 10: per-j overhead halves.
template <int NNZ, int RSTRIDE, int WOFF>
__global__ __launch_bounds__(512, 8) void k_layer(
    const uint8_t* __restrict__ pk,
    const float* __restrict__ bias,
    const float* __restrict__ tau_m,
    const float* __restrict__ tau_n,
    const uint64_t* __restrict__ inm,       // [DIN][TP]
    uint64_t* __restrict__ outm)            // [HID][TP]
{
    const int lane = threadIdx.x & 63;
    const int wid  = __builtin_amdgcn_readfirstlane(threadIdx.x >> 6); // 0..7
    const int h    = blockIdx.x;
    const int r    = h * NBR + wid;

    __shared__ uint2 ent[NBR * NNZ];
    __shared__ float red[2][NBR * CH * 64];

    inm = (const uint64_t*)__builtin_assume_aligned(inm, 64);

    {
        const uint16_t* pidx = (const uint16_t*)(pk + (size_t)r * RSTRIDE);
        const float*    pw   = (const float*)(pk + (size_t)r * RSTRIDE + WOFF);
        for (int s = lane; s < NNZ; s += 64)
            ent[wid * NNZ + s] = make_uint2(__float_as_uint(pw[s]),
                                            (unsigned)pidx[s]);
    }
    __syncthreads();

    const float be = 1.f / (1.f + expf(-tau_n[r]));
    const float om = 1.f - be;
    const float bb = bias[r];
    const float al  = 1.f / (1.f + expf(-tau_m[h]));
    const float oma = 1.f - al;

    float d = 0.f, mem = 0.f, spkprev = 0.f;
    const int base = wid * NNZ;

    for (int pass = 0; pass < NPASS; ++pass) {
        const int t0 = pass * CH2;
        float a[CH2];
#pragma unroll
        for (int k = 0; k < CH2; ++k) a[k] = 0.f;

#pragma unroll 2
        for (int j = 0; j < NNZ; ++j) {
            const uint2 e  = ent[base + j];
            const int   ix = __builtin_amdgcn_readfirstlane((int)e.y);
            const float wv = __uint_as_float(e.x);
            const ulonglong4* p =
                (const ulonglong4*)(inm + (size_t)ix * TP + t0);
            const ulonglong4 q0 = p[0], q1 = p[1], q2 = p[2], q3 = p[3];
            const uint64_t m[CH2] = {q0.x, q0.y, q0.z, q0.w,
                                     q1.x, q1.y, q1.z, q1.w,
                                     q2.x, q2.y, q2.z, q2.w,
                                     q3.x, q3.y, q3.z, q3.w};
#pragma unroll
            for (int k = 0; k < CH2; ++k) {
                float s;
                asm("v_cndmask_b32 %0, 0, %1, %2"
                    : "=v"(s) : "v"(wv), "s"(m[k]));
                a[k] += s;
            }
        }

        // d-recursion for all 16 k; halves land in the two red buffers
#pragma unroll
        for (int k = 0; k < CH2; ++k) {
            d = be * d + om * (a[k] + bb);
            red[k >> 3][(wid * CH + (k & 7)) * 64 + lane] = d;
        }
        __syncthreads();

        if (wid == 0) {
#pragma unroll
            for (int k = 0; k < CH2; ++k) {
                const int bf = k >> 3, kk = k & 7;
                const float r0 = red[bf][(0 * CH + kk) * 64 + lane];
                const float r1 = red[bf][(1 * CH + kk) * 64 + lane];
                const float r2 = red[bf][(2 * CH + kk) * 64 + lane];
                const float r3 = red[bf][(3 * CH + kk) * 64 + lane];
                const float r4 = red[bf][(4 * CH + kk) * 64 + lane];
                const float r5 = red[bf][(5 * CH + kk) * 64 + lane];
                const float r6 = red[bf][(6 * CH + kk) * 64 + lane];
                const float r7 = red[bf][(7 * CH + kk) * 64 + lane];
                const float p01 = r0 + r1, p23 = r2 + r3;
                const float p45 = r4 + r5, p67 = r6 + r7;
                const float l = ((p01 + p23) + p45) + p67;
                if (t0 + k < TT) {
                    mem = al * mem + oma * l - spkprev;   // VTH = 1.0
                    spkprev = (mem > 1.0f) ? 1.f : 0.f;
                    const unsigned long long bal = __ballot(mem > 1.0f);
                    if (lane == 0) outm[(size_t)h * TP + (t0 + k)] = bal;
                }
            }
        }
        __syncthreads();   // protect red before next pass overwrites it
    }
}

// Y[t][o][b] = wr[o] . s3(t,:,b)
__global__ __launch_bounds__(256) void k_ry(const float* __restrict__ wr,
                                            const uint64_t* __restrict__ s3m,
                                            float* __restrict__ Y) {
    const int lane  = threadIdx.x & 63;
    const int wid   = __builtin_amdgcn_readfirstlane(threadIdx.x >> 6); // 0..3
    const int o  = blockIdx.x / NCHUNK;
    const int t0 = (blockIdx.x % NCHUNK) * CH;
    s3m = (const uint64_t*)__builtin_assume_aligned(s3m, 64);
    const float* wrow = wr + (size_t)o * HID;
    __shared__ float red[4 * CH * 64];
    float acc[CH];
#pragma unroll
    for (int k = 0; k < CH; ++k) acc[k] = 0.f;
#pragma unroll 4
    for (int ii = 0; ii < HID / 4; ++ii) {
        const int i = wid * (HID / 4) + ii;
        const float wv = wrow[i];
        const ulonglong4* p = (const ulonglong4*)(s3m + (size_t)i * TP + t0);
        const ulonglong4 ma = p[0], mb = p[1];
        const uint64_t m[CH] = {ma.x, ma.y, ma.z, ma.w, mb.x, mb.y, mb.z, mb.w};
#pragma unroll
        for (int k = 0; k < CH; ++k) {
            float s;
            asm("v_cndmask_b32 %0, 0, %1, %2" : "=v"(s) : "v"(wv), "s"(m[k]));
            acc[k] += s;
        }
    }
#pragma unroll
    for (int k = 0; k < CH; ++k)
        red[(wid * CH + k) * 64 + lane] = acc[k];
    __syncthreads();
    if (wid == 0) {
#pragma unroll
        for (int k = 0; k < CH; ++k) {
            if (t0 + k >= TT) break;
            const float v = ((red[(0 * CH + k) * 64 + lane]
                            + red[(1 * CH + k) * 64 + lane])
                            + red[(2 * CH + k) * 64 + lane])
                            + red[(3 * CH + k) * 64 + lane];
            Y[((size_t)(t0 + k) * OUTN + o) * 64 + lane] = v;
        }
    }
}

// acc[o][b] = sum_t (Y + br[o]) * (1 - ar^(150-t))
__global__ void k_racc(const float* __restrict__ Y,
                       const float* __restrict__ br,
                       const float* __restrict__ tau_mr,
                       float* __restrict__ ACC) {
    const int o = blockIdx.x, lane = threadIdx.x;
    const float ar  = 1.f / (1.f + expf(-tau_mr[o]));
    const float bro = br[o];
    float acc = 0.f, q = ar;
    for (int t = TT - 1; t >= 0; --t) {
        const float y = Y[((size_t)t * OUTN + o) * 64 + lane] + bro;
        acc += y * (1.f - q);
        q *= ar;
    }
    ACC[o * 64 + lane] = acc;
}

__global__ void k_smax(const float* __restrict__ ACC, float* __restrict__ out) {
    const int b = threadIdx.x;   // 64 threads
    float v[OUTN];
    float mx = -3.4e38f;
    for (int o = 0; o < OUTN; ++o) {
        v[o] = ACC[o * 64 + b] / (float)TT;
        mx = fmaxf(mx, v[o]);
    }
    float sum = 0.f;
    for (int o = 0; o < OUTN; ++o) sum += expf(v[o] - mx);
    const float lse = mx + logf(sum);
    for (int o = 0; o < OUTN; ++o) out[b * OUTN + o] = v[o] - lse;
}

extern "C" void kernel_launch(void* const* d_in, const int* in_sizes, int n_in,
                              void* d_out, int out_size, void* d_ws,
                              size_t ws_size, hipStream_t stream) {
    (void)in_sizes; (void)n_in; (void)out_size; (void)ws_size;
    const float* x   = (const float*)d_in[0];
    const float* w1  = (const float*)d_in[1];
    const float* b1  = (const float*)d_in[2];
    const float* tm1 = (const float*)d_in[3];
    const float* tn1 = (const float*)d_in[4];
    const float* w2  = (const float*)d_in[5];
    const float* b2  = (const float*)d_in[6];
    const float* tm2 = (const float*)d_in[7];
    const float* tn2 = (const float*)d_in[8];
    const float* w3  = (const float*)d_in[9];
    const float* b3  = (const float*)d_in[10];
    const float* tm3 = (const float*)d_in[11];
    const float* tn3 = (const float*)d_in[12];
    const float* wr  = (const float*)d_in[13];
    const float* br  = (const float*)d_in[14];
    const float* tmr = (const float*)d_in[15];
    const void*  m1  = d_in[16];
    const void*  m2  = d_in[17];
    const void*  m3  = d_in[18];
    float* out = (float*)d_out;

    char* ws = (char*)d_ws;
    uint64_t* sA  = (uint64_t*)(ws + SA_OFF);   // s1m, later s3m
    uint64_t* sB  = (uint64_t*)(ws + SB_OFF);   // s2m
    uint8_t*  PK  = (uint8_t*)(ws + PK_OFF);    // PK1 / PK2 / PK3
    float*    xT  = (float*)(ws + XT_OFF);
    float*    Y   = (float*)(ws + Y_OFF);
    float*    ACC = (float*)(ws + ACC_OFF);

    // layer 1 (dense input)
    k_pack<INSZ, 15, 16, 128, 32><<<HID, 512, 0, stream>>>(w1, m1, PK);
    k_tx<<<TT, 256, 0, stream>>>(x, xT);
    k_l1<<<HID, 512, 0, stream>>>(PK, b1, tm1, tn1, xT, sA);
    // layer 2 (PK slot reused; xT/PK1 dead)
    k_pack<HID, 128, 128, 768, 256><<<HID, 512, 0, stream>>>(w2, m2, PK);
    k_layer<128, 768, 256><<<HID, 512, 0, stream>>>(PK, b2, tm2, tn2, sA, sB);
    // layer 3 (PK reused again; s3m over dead s1m)
    k_pack<HID, 128, 128, 768, 256><<<HID, 512, 0, stream>>>(w3, m3, PK);
    k_layer<128, 768, 256><<<HID, 512, 0, stream>>>(PK, b3, tm3, tn3, sB, sA);
    // readout (Y over dead PK)
    k_ry<<<OUTN * NCHUNK, 256, 0, stream>>>(wr, sA, Y);
    k_racc<<<OUTN, 64, 0, stream>>>(Y, br, tmr, ACC);
    k_smax<<<1, 64, 0, stream>>>(ACC, out);
}

// Round 10
// 1711.106 us; speedup vs baseline: 1.3213x; 1.0079x over previous
//
#include <hip/hip_runtime.h>
#include <stdint.h>

#define TT     150
#define INSZ   120
#define HID    1024
#define OUTN   35
#define NBR    8
#define TP     160     // padded time steps; mask row = 1280 B
#define CH     8
#define NCHUNK 19

// ------------- ws map (bytes) — aliased, peak 8.91 MB (r9-verified) -------
#define SA_OFF   0
#define SB_OFF   1310720
#define PK_OFF   2621440
#define XT_OFF   3670016
#define Y_OFF    2621440
#define ACC_OFF  3965440

// ---- pack masked rows into {idx u16[NNZ_OUT], w f32[NNZ_OUT]} streams ----
template <int DIN, int NNZ_EXPECT, int NNZ_OUT, int RSTRIDE, int WOFF>
__global__ __launch_bounds__(512) void k_pack(
    const float* __restrict__ w, const void* __restrict__ maskp,
    uint8_t* __restrict__ dst) {
    const int lane = threadIdx.x & 63;
    const int wid  = __builtin_amdgcn_readfirstlane(threadIdx.x >> 6);
    const int r    = blockIdx.x * 8 + wid;
    uint16_t* di = (uint16_t*)(dst + (size_t)r * RSTRIDE);
    float*    dw = (float*)(dst + (size_t)r * RSTRIDE + WOFF);
    const unsigned char* m8  = (const unsigned char*)maskp;
    const int*           m32 = (const int*)maskp;

    int cnt = 0;
    for (int c = 0; c * 64 < DIN; ++c) {
        const int i = c * 64 + lane;
        int   mv = 0; float wv = 0.f;
        if (i < DIN) { mv = m8[(size_t)r * DIN + i]; wv = w[(size_t)r * DIN + i]; }
        const unsigned long long bal = __ballot(mv != 0);
        const int pos = __popcll(bal & ((1ull << lane) - 1ull));
        if (mv && cnt + pos < NNZ_OUT) { di[cnt + pos] = (uint16_t)i; dw[cnt + pos] = wv; }
        cnt += __popcll(bal);
    }
    if (cnt != NNZ_EXPECT) {          // masks are int32 after all
        cnt = 0;
        for (int c = 0; c * 64 < DIN; ++c) {
            const int i = c * 64 + lane;
            int   mv = 0; float wv = 0.f;
            if (i < DIN) { mv = m32[(size_t)r * DIN + i]; wv = w[(size_t)r * DIN + i]; }
            const unsigned long long bal = __ballot(mv != 0);
            const int pos = __popcll(bal & ((1ull << lane) - 1ull));
            if (mv && cnt + pos < NNZ_OUT) { di[cnt + pos] = (uint16_t)i; dw[cnt + pos] = wv; }
            cnt += __popcll(bal);
        }
    }
    for (int f = cnt + lane; f < NNZ_OUT; f += 64) { di[f] = 0; dw[f] = 0.f; }
}

// transpose x[b][0][t][i] -> xT[t][i][b], LDS-tiled
__global__ __launch_bounds__(256) void k_tx(const float* __restrict__ x,
                                            float* __restrict__ xT) {
    const int t = blockIdx.x;
    __shared__ float tile[INSZ * 65];
    for (int e = threadIdx.x; e < INSZ * 64; e += 256) {
        const int b = e / INSZ, i = e - b * INSZ;
        tile[i * 65 + b] = x[((size_t)b * TT + t) * INSZ + i];
    }
    __syncthreads();
    for (int e = threadIdx.x; e < INSZ * 64; e += 256) {
        const int i = e >> 6, b = e & 63;
        xT[((size_t)t * INSZ + i) * 64 + b] = tile[i * 65 + b];
    }
}

// Layer 1 (dense input) — r9-proven: scalars hoisted, k-loop unroll(1),
// <=16 live loads -> cannot spill.
__global__ __launch_bounds__(512, 8) void k_l1(
    const uint8_t* __restrict__ pk,
    const float* __restrict__ bias,
    const float* __restrict__ tau_m,
    const float* __restrict__ tau_n,
    const float* __restrict__ xin,          // [T][INSZ][64]
    uint64_t* __restrict__ outm)            // [HID][TP]
{
    const int lane = threadIdx.x & 63;
    const int wid  = __builtin_amdgcn_readfirstlane(threadIdx.x >> 6); // 0..7
    const int h    = blockIdx.x;
    const int r    = h * NBR + wid;

    __shared__ float red[2][NBR * CH * 64];

    const uint16_t* pidx = (const uint16_t*)(pk + (size_t)r * 128);
    const float*    pw   = (const float*)(pk + (size_t)r * 128 + 32);
    const float* rp[16];
    float wv[16];
#pragma unroll
    for (int j = 0; j < 16; ++j) {
        const int ix = __builtin_amdgcn_readfirstlane((int)pidx[j]);
        rp[j] = xin + ix * 64;
        wv[j] = __uint_as_float(
            __builtin_amdgcn_readfirstlane((int)__float_as_uint(pw[j])));
    }

    const float be = 1.f / (1.f + expf(-tau_n[r]));
    const float om = 1.f - be;
    const float bb = bias[r];
    const float al  = 1.f / (1.f + expf(-tau_m[h]));
    const float oma = 1.f - al;

    float d = 0.f, mem = 0.f, spkprev = 0.f;

    for (int tc = 0; tc < NCHUNK; ++tc) {
        const int t0  = tc * CH;
        const int buf = tc & 1;

#pragma unroll 1
        for (int k = 0; k < CH; ++k) {
            const int tofs = (t0 + k) * (INSZ * 64) + lane;
            float s = 0.f;
#pragma unroll
            for (int j = 0; j < 16; ++j)
                s += wv[j] * rp[j][tofs];      // same order as reference sum
            d = be * d + om * (s + bb);
            red[buf][(wid * CH + k) * 64 + lane] = d;
        }
        __syncthreads();

        if (wid == 0) {
#pragma unroll
            for (int k = 0; k < CH; ++k) {
                const float r0 = red[buf][(0 * CH + k) * 64 + lane];
                const float r1 = red[buf][(1 * CH + k) * 64 + lane];
                const float r2 = red[buf][(2 * CH + k) * 64 + lane];
                const float r3 = red[buf][(3 * CH + k) * 64 + lane];
                const float r4 = red[buf][(4 * CH + k) * 64 + lane];
                const float r5 = red[buf][(5 * CH + k) * 64 + lane];
                const float r6 = red[buf][(6 * CH + k) * 64 + lane];
                const float r7 = red[buf][(7 * CH + k) * 64 + lane];
                const float p01 = r0 + r1, p23 = r2 + r3;
                const float p45 = r4 + r5, p67 = r6 + r7;
                const float l = ((p01 + p23) + p45) + p67;
                if (t0 + k < TT) {
                    mem = al * mem + oma * l - spkprev;   // VTH = 1.0
                    spkprev = (mem > 1.0f) ? 1.f : 0.f;
                    const unsigned long long bal = __ballot(mem > 1.0f);
                    if (lane == 0) outm[(size_t)h * TP + (t0 + k)] = bal;
                }
            }
        }
    }
}

// Spike-input layer (layers 2/3) — r7-proven body (604 us).
// JUNROLL A/B: layer2=4 (r7 exact), layer3=8 (more SMEM in flight).
template <int NNZ, int RSTRIDE, int WOFF, int JUNROLL>
__global__ __launch_bounds__(512, 8) void k_layer(
    const uint8_t* __restrict__ pk,
    const float* __restrict__ bias,
    const float* __restrict__ tau_m,
    const float* __restrict__ tau_n,
    const uint64_t* __restrict__ inm,       // [DIN][TP]
    uint64_t* __restrict__ outm)            // [HID][TP]
{
    const int lane = threadIdx.x & 63;
    const int wid  = __builtin_amdgcn_readfirstlane(threadIdx.x >> 6); // 0..7
    const int h    = blockIdx.x;
    const int r    = h * NBR + wid;

    __shared__ uint2 ent[NBR * NNZ];
    __shared__ float red[2][NBR * CH * 64];

    inm = (const uint64_t*)__builtin_assume_aligned(inm, 64);

    {
        const uint16_t* pidx = (const uint16_t*)(pk + (size_t)r * RSTRIDE);
        const float*    pw   = (const float*)(pk + (size_t)r * RSTRIDE + WOFF);
        for (int s = lane; s < NNZ; s += 64)
            ent[wid * NNZ + s] = make_uint2(__float_as_uint(pw[s]),
                                            (unsigned)pidx[s]);
    }
    __syncthreads();

    const float be = 1.f / (1.f + expf(-tau_n[r]));
    const float om = 1.f - be;
    const float bb = bias[r];
    const float al  = 1.f / (1.f + expf(-tau_m[h]));
    const float oma = 1.f - al;

    float d = 0.f, mem = 0.f, spkprev = 0.f;
    const int base = wid * NNZ;

    for (int tc = 0; tc < NCHUNK; ++tc) {
        const int t0  = tc * CH;
        const int buf = tc & 1;
        float a[CH];
#pragma unroll
        for (int k = 0; k < CH; ++k) a[k] = 0.f;

        if constexpr (JUNROLL == 8) {
#pragma unroll 8
            for (int j = 0; j < NNZ; ++j) {
                const uint2 e  = ent[base + j];
                const int   ix = __builtin_amdgcn_readfirstlane((int)e.y);
                const float wv = __uint_as_float(e.x);
                const ulonglong4* p =
                    (const ulonglong4*)(inm + (size_t)ix * TP + t0);
                const ulonglong4 ma = p[0], mb = p[1];
                const uint64_t m[CH] = {ma.x, ma.y, ma.z, ma.w,
                                        mb.x, mb.y, mb.z, mb.w};
#pragma unroll
                for (int k = 0; k < CH; ++k) {
                    float s;
                    asm("v_cndmask_b32 %0, 0, %1, %2"
                        : "=v"(s) : "v"(wv), "s"(m[k]));
                    a[k] += s;
                }
            }
        } else {
#pragma unroll 4
            for (int j = 0; j < NNZ; ++j) {
                const uint2 e  = ent[base + j];
                const int   ix = __builtin_amdgcn_readfirstlane((int)e.y);
                const float wv = __uint_as_float(e.x);
                const ulonglong4* p =
                    (const ulonglong4*)(inm + (size_t)ix * TP + t0);
                const ulonglong4 ma = p[0], mb = p[1];
                const uint64_t m[CH] = {ma.x, ma.y, ma.z, ma.w,
                                        mb.x, mb.y, mb.z, mb.w};
#pragma unroll
                for (int k = 0; k < CH; ++k) {
                    float s;
                    asm("v_cndmask_b32 %0, 0, %1, %2"
                        : "=v"(s) : "v"(wv), "s"(m[k]));
                    a[k] += s;
                }
            }
        }

#pragma unroll
        for (int k = 0; k < CH; ++k) {
            d = be * d + om * (a[k] + bb);
            red[buf][(wid * CH + k) * 64 + lane] = d;
        }
        __syncthreads();

        if (wid == 0) {
#pragma unroll
            for (int k = 0; k < CH; ++k) {
                const float r0 = red[buf][(0 * CH + k) * 64 + lane];
                const float r1 = red[buf][(1 * CH + k) * 64 + lane];
                const float r2 = red[buf][(2 * CH + k) * 64 + lane];
                const float r3 = red[buf][(3 * CH + k) * 64 + lane];
                const float r4 = red[buf][(4 * CH + k) * 64 + lane];
                const float r5 = red[buf][(5 * CH + k) * 64 + lane];
                const float r6 = red[buf][(6 * CH + k) * 64 + lane];
                const float r7 = red[buf][(7 * CH + k) * 64 + lane];
                const float p01 = r0 + r1, p23 = r2 + r3;
                const float p45 = r4 + r5, p67 = r6 + r7;
                const float l = ((p01 + p23) + p45) + p67;
                if (t0 + k < TT) {
                    mem = al * mem + oma * l - spkprev;   // VTH = 1.0
                    spkprev = (mem > 1.0f) ? 1.f : 0.f;
                    const unsigned long long bal = __ballot(mem > 1.0f);
                    if (lane == 0) outm[(size_t)h * TP + (t0 + k)] = bal;
                }
            }
        }
    }
}

// Y[t][o][b] = wr[o] . s3(t,:,b)
__global__ __launch_bounds__(256) void k_ry(const float* __restrict__ wr,
                                            const uint64_t* __restrict__ s3m,
                                            float* __restrict__ Y) {
    const int lane  = threadIdx.x & 63;
    const int wid   = __builtin_amdgcn_readfirstlane(threadIdx.x >> 6); // 0..3
    const int o  = blockIdx.x / NCHUNK;
    const int t0 = (blockIdx.x % NCHUNK) * CH;
    s3m = (const uint64_t*)__builtin_assume_aligned(s3m, 64);
    const float* wrow = wr + (size_t)o * HID;
    __shared__ float red[4 * CH * 64];
    float acc[CH];
#pragma unroll
    for (int k = 0; k < CH; ++k) acc[k] = 0.f;
#pragma unroll 4
    for (int ii = 0; ii < HID / 4; ++ii) {
        const int i = wid * (HID / 4) + ii;
        const float wv = wrow[i];
        const ulonglong4* p = (const ulonglong4*)(s3m + (size_t)i * TP + t0);
        const ulonglong4 ma = p[0], mb = p[1];
        const uint64_t m[CH] = {ma.x, ma.y, ma.z, ma.w, mb.x, mb.y, mb.z, mb.w};
#pragma unroll
        for (int k = 0; k < CH; ++k) {
            float s;
            asm("v_cndmask_b32 %0, 0, %1, %2" : "=v"(s) : "v"(wv), "s"(m[k]));
            acc[k] += s;
        }
    }
#pragma unroll
    for (int k = 0; k < CH; ++k)
        red[(wid * CH + k) * 64 + lane] = acc[k];
    __syncthreads();
    if (wid == 0) {
#pragma unroll
        for (int k = 0; k < CH; ++k) {
            if (t0 + k >= TT) break;
            const float v = ((red[(0 * CH + k) * 64 + lane]
                            + red[(1 * CH + k) * 64 + lane])
                            + red[(2 * CH + k) * 64 + lane])
                            + red[(3 * CH + k) * 64 + lane];
            Y[((size_t)(t0 + k) * OUTN + o) * 64 + lane] = v;
        }
    }
}

// acc[o][b] = sum_t (Y + br[o]) * (1 - ar^(150-t))
__global__ void k_racc(const float* __restrict__ Y,
                       const float* __restrict__ br,
                       const float* __restrict__ tau_mr,
                       float* __restrict__ ACC) {
    const int o = blockIdx.x, lane = threadIdx.x;
    const float ar  = 1.f / (1.f + expf(-tau_mr[o]));
    const float bro = br[o];
    float acc = 0.f, q = ar;
    for (int t = TT - 1; t >= 0; --t) {
        const float y = Y[((size_t)t * OUTN + o) * 64 + lane] + bro;
        acc += y * (1.f - q);
        q *= ar;
    }
    ACC[o * 64 + lane] = acc;
}

__global__ void k_smax(const float* __restrict__ ACC, float* __restrict__ out) {
    const int b = threadIdx.x;   // 64 threads
    float v[OUTN];
    float mx = -3.4e38f;
    for (int o = 0; o < OUTN; ++o) {
        v[o] = ACC[o * 64 + b] / (float)TT;
        mx = fmaxf(mx, v[o]);
    }
    float sum = 0.f;
    for (int o = 0; o < OUTN; ++o) sum += expf(v[o] - mx);
    const float lse = mx + logf(sum);
    for (int o = 0; o < OUTN; ++o) out[b * OUTN + o] = v[o] - lse;
}

extern "C" void kernel_launch(void* const* d_in, const int* in_sizes, int n_in,
                              void* d_out, int out_size, void* d_ws,
                              size_t ws_size, hipStream_t stream) {
    (void)in_sizes; (void)n_in; (void)out_size; (void)ws_size;
    const float* x   = (const float*)d_in[0];
    const float* w1  = (const float*)d_in[1];
    const float* b1  = (const float*)d_in[2];
    const float* tm1 = (const float*)d_in[3];
    const float* tn1 = (const float*)d_in[4];
    const float* w2  = (const float*)d_in[5];
    const float* b2  = (const float*)d_in[6];
    const float* tm2 = (const float*)d_in[7];
    const float* tn2 = (const float*)d_in[8];
    const float* w3  = (const float*)d_in[9];
    const float* b3  = (const float*)d_in[10];
    const float* tm3 = (const float*)d_in[11];
    const float* tn3 = (const float*)d_in[12];
    const float* wr  = (const float*)d_in[13];
    const float* br  = (const float*)d_in[14];
    const float* tmr = (const float*)d_in[15];
    const void*  m1  = d_in[16];
    const void*  m2  = d_in[17];
    const void*  m3  = d_in[18];
    float* out = (float*)d_out;

    char* ws = (char*)d_ws;
    uint64_t* sA  = (uint64_t*)(ws + SA_OFF);   // s1m, later s3m
    uint64_t* sB  = (uint64_t*)(ws + SB_OFF);   // s2m
    uint8_t*  PK  = (uint8_t*)(ws + PK_OFF);    // PK1 / PK2 / PK3
    float*    xT  = (float*)(ws + XT_OFF);
    float*    Y   = (float*)(ws + Y_OFF);
    float*    ACC = (float*)(ws + ACC_OFF);

    // layer 1 (dense input)
    k_pack<INSZ, 15, 16, 128, 32><<<HID, 512, 0, stream>>>(w1, m1, PK);
    k_tx<<<TT, 256, 0, stream>>>(x, xT);
    k_l1<<<HID, 512, 0, stream>>>(PK, b1, tm1, tn1, xT, sA);
    // layer 2 (PK slot reused; xT/PK1 dead) — JUNROLL=4 (r7 exact)
    k_pack<HID, 128, 128, 768, 256><<<HID, 512, 0, stream>>>(w2, m2, PK);
    k_layer<128, 768, 256, 4><<<HID, 512, 0, stream>>>(PK, b2, tm2, tn2, sA, sB);
    // layer 3 (PK reused; s3m over dead s1m) — JUNROLL=8 (A/B arm)
    k_pack<HID, 128, 128, 768, 256><<<HID, 512, 0, stream>>>(w3, m3, PK);
    k_layer<128, 768, 256, 8><<<HID, 512, 0, stream>>>(PK, b3, tm3, tn3, sB, sA);
    // readout (Y over dead PK)
    k_ry<<<OUTN * NCHUNK, 256, 0, stream>>>(wr, sA, Y);
    k_racc<<<OUTN, 64, 0, stream>>>(Y, br, tmr, ACC);
    k_smax<<<1, 64, 0, stream>>>(ACC, out);
}